// Round 7
// baseline (265.886 us; speedup 1.0000x reference)
//
#include <hip/hip_runtime.h>
#include <cstddef>
#include <cstdint>

#define NN 6144
#define FF 512
#define HH 128
#define CCC 16
#define KTOP 50
#define GCB 256   // gated-chain blocks (<=256 -> co-resident guaranteed)

typedef __attribute__((ext_vector_type(8))) short bf16x8;
typedef __attribute__((ext_vector_type(4))) float f32x4;
typedef __attribute__((ext_vector_type(4))) ushort u16x4;
typedef __attribute__((ext_vector_type(8))) ushort u16x8;

// ---------------------------------------------------------------- helpers
__device__ __forceinline__ float wave_sum(float v) {
  #pragma unroll
  for (int o = 32; o; o >>= 1) v += __shfl_down(v, o);
  return v;
}

__device__ __forceinline__ ushort f2b(float x) {   // fp32 -> bf16 RNE
  union { float f; uint32_t u; } v; v.f = x;
  const uint32_t r = v.u + 0x7FFFu + ((v.u >> 16) & 1u);
  return (ushort)(r >> 16);
}

// ---------------------------------------------------------------- flag + e + weight transposes + zero barrier counters
__global__ __launch_bounds__(256) void k_flag_prep(const float* __restrict__ u,
                                                   const float* __restrict__ delta,
                                                   float* __restrict__ e,
                                                   int* __restrict__ flag,
                                                   int* __restrict__ cnt,
                                                   const float* __restrict__ W1,
                                                   const float* __restrict__ W2,
                                                   ushort* __restrict__ W1T,
                                                   ushort* __restrict__ W2T) {
  const int b = blockIdx.x, t = threadIdx.x;
  if (b < 256) {                       // weight transposes: FF*HH = 65536 = 256*256
    const int idx = b * 256 + t;
    const int rr = idx >> 7, cc = idx & 127;
    W1T[(size_t)cc * FF + rr] = f2b(W1[idx]);
    if (idx < HH * CCC) {
      const int r2 = idx >> 4, c2 = idx & 15;
      W2T[(size_t)c2 * HH + r2] = f2b(W2[idx]);
    }
    return;
  }
  // flag block
  if (t < 8) cnt[t] = 0;
  float emax = -1e30f, dmin = 1e30f;
  for (int j = t; j < NN; j += 256) {
    float ev = expf(-u[j]);
    e[j] = ev;
    emax = fmaxf(emax, ev);
    dmin = fminf(dmin, delta[j]);
  }
  #pragma unroll
  for (int o = 32; o; o >>= 1) {
    emax = fmaxf(emax, __shfl_down(emax, o));
    dmin = fminf(dmin, __shfl_down(dmin, o));
  }
  __shared__ float sm[4], sn[4];
  if ((t & 63) == 0) { sm[t >> 6] = emax; sn[t >> 6] = dmin; }
  __syncthreads();
  if (t == 0) {
    emax = fmaxf(fmaxf(sm[0], sm[1]), fmaxf(sm[2], sm[3]));
    dmin = fminf(fminf(sn[0], sn[1]), fminf(sn[2], sn[3]));
    flag[0] = (emax >= dmin || dmin <= 0.0f) ? 1 : 0;
  }
}

// ---------------------------------------------------------------- gated chain: ONE dispatch, software phase barriers.
__device__ __forceinline__ void gbar(int* cnt, int phase) {
  __syncthreads();
  if (threadIdx.x == 0) {
    __threadfence();
    atomicAdd(&cnt[phase], 1);
    while (atomicAdd(&cnt[phase], 0) < GCB) { __builtin_amdgcn_s_sleep(8); }
    __threadfence();
  }
  __syncthreads();
}

__global__ __launch_bounds__(256) void k_gated_chain(const float* __restrict__ Adj,
                                                     const float* __restrict__ in,
                                                     const float* __restrict__ w1,
                                                     const float* __restrict__ w2,
                                                     float* __restrict__ dinv,
                                                     float* __restrict__ dsq,
                                                     float* __restrict__ X1,
                                                     float* __restrict__ X2,
                                                     float* __restrict__ EMBP,
                                                     float* __restrict__ EMBN,
                                                     float* __restrict__ afin,   // sim scratch
                                                     float* __restrict__ anew,
                                                     float* __restrict__ VALS,
                                                     int* __restrict__ IDX,
                                                     int* __restrict__ cnt,
                                                     const int* __restrict__ gate) {
  if (gate[0] == 0) return;
  const int t = threadIdx.x, bid = blockIdx.x;
  __shared__ union {
    struct { float As[64][33]; float Xs[32][128]; } g;
    struct { float Ui[64][33]; float Uj[64][33]; } s;
    struct { float sv[NN]; } k;
  } u;
  __shared__ float sm[4];
  __shared__ float fsh;
  __shared__ int bj4[4];
  __shared__ float bw[4];

  // P0: row sums of Adj + prescale input
  for (int row = bid; row < NN; row += GCB) {
    const float4* Ar = (const float4*)(Adj + (size_t)row * NN);
    float s = 0.f;
    for (int j = t; j < NN / 4; j += 256) {
      float4 v = Ar[j];
      s += v.x + v.y + v.z + v.w;
    }
    s = wave_sum(s);
    if ((t & 63) == 0) sm[t >> 6] = s;
    __syncthreads();
    if (t == 0) {
      float tot = sm[0] + sm[1] + sm[2] + sm[3];
      float dv = tot > 0.f ? 1.0f / sqrtf(tot) : 0.0f;
      dinv[row] = dv; dsq[row] = dv * dv; fsh = dv;
    }
    __syncthreads();
    const float d = fsh;
    if (t < FF / 4) {
      float4 v = ((const float4*)(in + (size_t)row * FF))[t];
      float4 w = ((const float4*)w1)[t];
      v.x *= d * w.x; v.y *= d * w.y; v.z *= d * w.z; v.w *= d * w.w;
      ((float4*)(X1 + (size_t)row * FF))[t] = v;
    }
    __syncthreads();
  }
  gbar(cnt, 0);

  // P1/P2: two fp32 GEMMs (A=Adj [NN][NN], X [NN][FF], BN=128 tiles)
  const int tx = t & 15, ty = t >> 4;
  for (int pass = 0; pass < 2; ++pass) {
    const float* Xsrc = pass == 0 ? X1 : X2;
    float* Cdst = pass == 0 ? X2 : EMBP;
    for (int tile = bid; tile < (NN / 64) * (FF / 128); tile += GCB) {
      const int row0 = (tile / 4) * 64, col0 = (tile % 4) * 128;
      float acc[4][8];
      #pragma unroll
      for (int i = 0; i < 4; ++i)
        #pragma unroll
        for (int j = 0; j < 8; ++j) acc[i][j] = 0.f;
      for (int k0 = 0; k0 < NN; k0 += 32) {
        #pragma unroll
        for (int s = t; s < 512; s += 256) {
          const int r = s >> 3, q = s & 7;
          float4 v = *(const float4*)(Adj + (size_t)(row0 + r) * NN + k0 + q * 4);
          u.g.As[r][q * 4 + 0] = v.x; u.g.As[r][q * 4 + 1] = v.y;
          u.g.As[r][q * 4 + 2] = v.z; u.g.As[r][q * 4 + 3] = v.w;
        }
        for (int s = t; s < 32 * 32; s += 256) {
          const int r = s >> 5, q = s & 31;
          *(float4*)&u.g.Xs[r][q * 4] = *(const float4*)(Xsrc + (size_t)(k0 + r) * FF + col0 + q * 4);
        }
        __syncthreads();
        #pragma unroll
        for (int kk = 0; kk < 32; ++kk) {
          float a[4];
          #pragma unroll
          for (int i = 0; i < 4; ++i) a[i] = u.g.As[ty * 4 + i][kk];
          float4 x0 = *(float4*)&u.g.Xs[kk][tx * 8];
          float4 x1 = *(float4*)&u.g.Xs[kk][tx * 8 + 4];
          #pragma unroll
          for (int i = 0; i < 4; ++i) {
            acc[i][0] += a[i] * x0.x; acc[i][1] += a[i] * x0.y;
            acc[i][2] += a[i] * x0.z; acc[i][3] += a[i] * x0.w;
            acc[i][4] += a[i] * x1.x; acc[i][5] += a[i] * x1.y;
            acc[i][6] += a[i] * x1.z; acc[i][7] += a[i] * x1.w;
          }
        }
        __syncthreads();
      }
      #pragma unroll
      for (int i = 0; i < 4; ++i)
        #pragma unroll
        for (int j = 0; j < 8; ++j) {
          const int r = row0 + ty * 4 + i, c = col0 + tx * 8 + j;
          float v = acc[i][j];
          if (pass == 0) v *= dsq[r] * w2[c];
          Cdst[(size_t)r * FF + c] = v;
        }
    }
    gbar(cnt, pass + 1);
  }

  // P3: row-normalize embeddings
  for (int row = bid; row < NN; row += GCB) {
    const float d = dinv[row];
    const float v0 = EMBP[(size_t)row * FF + t] * d;
    const float v1 = EMBP[(size_t)row * FF + 256 + t] * d;
    float ss = wave_sum(v0 * v0 + v1 * v1);
    if ((t & 63) == 0) sm[t >> 6] = ss;
    __syncthreads();
    if (t == 0) {
      const float nrm = sqrtf(sm[0] + sm[1] + sm[2] + sm[3]);
      fsh = 1.0f / fmaxf(nrm, 1e-12f);
    }
    __syncthreads();
    const float inv = fsh;
    EMBN[(size_t)row * FF + t] = v0 * inv;
    EMBN[(size_t)row * FF + 256 + t] = v1 * inv;
    __syncthreads();
  }
  gbar(cnt, 3);

  // P4: sim = U U^T (64x64 tiles) into afin scratch; also zero anew
  for (size_t i = (size_t)bid * 256 + t; i < (size_t)NN * NN / 4; i += (size_t)GCB * 256)
    ((f32x4*)anew)[i] = f32x4{0.f, 0.f, 0.f, 0.f};
  for (int tile = bid; tile < 96 * 96; tile += GCB) {
    const int bi = (tile / 96) * 64, bj = (tile % 96) * 64;
    float acc[4][4];
    #pragma unroll
    for (int i = 0; i < 4; ++i)
      #pragma unroll
      for (int j = 0; j < 4; ++j) acc[i][j] = 0.f;
    for (int k0 = 0; k0 < FF; k0 += 32) {
      #pragma unroll
      for (int s = t; s < 512; s += 256) {
        const int r = s >> 3, q = s & 7;
        float4 v = *(const float4*)(EMBN + (size_t)(bi + r) * FF + k0 + q * 4);
        u.s.Ui[r][q * 4 + 0] = v.x; u.s.Ui[r][q * 4 + 1] = v.y;
        u.s.Ui[r][q * 4 + 2] = v.z; u.s.Ui[r][q * 4 + 3] = v.w;
        float4 w = *(const float4*)(EMBN + (size_t)(bj + r) * FF + k0 + q * 4);
        u.s.Uj[r][q * 4 + 0] = w.x; u.s.Uj[r][q * 4 + 1] = w.y;
        u.s.Uj[r][q * 4 + 2] = w.z; u.s.Uj[r][q * 4 + 3] = w.w;
      }
      __syncthreads();
      #pragma unroll
      for (int kk = 0; kk < 32; ++kk) {
        float a[4], b[4];
        #pragma unroll
        for (int i = 0; i < 4; ++i) a[i] = u.s.Ui[ty * 4 + i][kk];
        #pragma unroll
        for (int j = 0; j < 4; ++j) b[j] = u.s.Uj[tx * 4 + j][kk];
        #pragma unroll
        for (int i = 0; i < 4; ++i)
          #pragma unroll
          for (int j = 0; j < 4; ++j) acc[i][j] += a[i] * b[j];
      }
      __syncthreads();
    }
    #pragma unroll
    for (int i = 0; i < 4; ++i)
      #pragma unroll
      for (int j = 0; j < 4; ++j)
        afin[(size_t)(bi + ty * 4 + i) * NN + bj + tx * 4 + j] = acc[i][j];
  }
  gbar(cnt, 4);

  // P5: top-50 per row
  for (int row = bid; row < NN; row += GCB) {
    const float* sr = afin + (size_t)row * NN;
    for (int j = t; j < NN; j += 256) u.k.sv[j] = sr[j];
    __syncthreads();
    for (int it = 0; it < KTOP; ++it) {
      float bv = -3.4e38f; int bj = NN;
      for (int j = t; j < NN; j += 256) {
        const float v = u.k.sv[j];
        if (v > bv || (v == bv && j < bj)) { bv = v; bj = j; }
      }
      #pragma unroll
      for (int o = 32; o; o >>= 1) {
        const float ov = __shfl_down(bv, o);
        const int oj = __shfl_down(bj, o);
        if (ov > bv || (ov == bv && oj < bj)) { bv = ov; bj = oj; }
      }
      if ((t & 63) == 0) { bw[t >> 6] = bv; bj4[t >> 6] = bj; }
      __syncthreads();
      if (t == 0) {
        #pragma unroll
        for (int q = 1; q < 4; ++q)
          if (bw[q] > bv || (bw[q] == bv && bj4[q] < bj)) { bv = bw[q]; bj = bj4[q]; }
        VALS[row * KTOP + it] = bv;
        IDX[row * KTOP + it] = bj;
        u.k.sv[bj] = -3.4e38f;
      }
      __syncthreads();
    }
  }
  gbar(cnt, 5);

  // P6: scatter-symmetrize
  for (int tid = bid * 256 + t; tid < NN * KTOP; tid += GCB * 256) {
    const int i = tid / KTOP;
    const float v = VALS[tid] * 0.5f;
    const int j = IDX[tid];
    atomicAdd(anew + (size_t)i * NN + j, v);
    atomicAdd(anew + (size_t)j * NN + i, v);
  }
}

// ---------------------------------------------------------------- mask + fuse + row sums + bf16 sidecar (always)
__device__ __forceinline__ float maskval(float a, float ev, float di, float m0) {
  if (a > 0.0f) {
    const float w = 2.0f / (1.0f + expf(di - ev));
    return (w >= 1.0f) ? a * w : 0.0f;
  }
  return a * m0;
}

__global__ __launch_bounds__(256) void k_mask_final(float* __restrict__ anew,
                                                    const float* __restrict__ adj,
                                                    const float* __restrict__ e,
                                                    const float* __restrict__ delta,
                                                    float* __restrict__ afin,
                                                    ushort* __restrict__ afb,
                                                    float* __restrict__ dinv2f,
                                                    const int* __restrict__ gate) {
  const int row = blockIdx.x, t = threadIdx.x;
  const bool fl = gate[0] != 0;
  const float di = delta[row];
  const float w0 = 2.0f / (1.0f + expf(di));
  const float m0 = (w0 >= 1.0f) ? w0 : 0.0f;
  const f32x4* ar = (const f32x4*)(adj + (size_t)row * NN);
  f32x4* an = (f32x4*)(anew + (size_t)row * NN);
  f32x4* af = (f32x4*)(afin + (size_t)row * NN);
  ushort* ab = afb + (size_t)row * NN;
  const f32x4* ef = (const f32x4*)e;
  float s = 0.f;
  #pragma unroll
  for (int i = 0; i < 3; ++i) {                 // 8 elems/thread/iter
    const int j = i * 256 + t;                  // j in [0,768)
    f32x4 a0 = fl ? an[2 * j] : f32x4{0.f, 0.f, 0.f, 0.f};
    f32x4 a1 = fl ? an[2 * j + 1] : f32x4{0.f, 0.f, 0.f, 0.f};
    const f32x4 d0 = __builtin_nontemporal_load(ar + 2 * j);
    const f32x4 d1 = __builtin_nontemporal_load(ar + 2 * j + 1);
    const f32x4 e0 = ef[2 * j];
    const f32x4 e1 = ef[2 * j + 1];
    f32x4 o0, o1, g0, g1;
    o0.x = maskval(a0.x, e0.x, di, m0); g0.x = o0.x + d0.x;
    o0.y = maskval(a0.y, e0.y, di, m0); g0.y = o0.y + d0.y;
    o0.z = maskval(a0.z, e0.z, di, m0); g0.z = o0.z + d0.z;
    o0.w = maskval(a0.w, e0.w, di, m0); g0.w = o0.w + d0.w;
    o1.x = maskval(a1.x, e1.x, di, m0); g1.x = o1.x + d1.x;
    o1.y = maskval(a1.y, e1.y, di, m0); g1.y = o1.y + d1.y;
    o1.z = maskval(a1.z, e1.z, di, m0); g1.z = o1.z + d1.z;
    o1.w = maskval(a1.w, e1.w, di, m0); g1.w = o1.w + d1.w;
    s += g0.x + g0.y + g0.z + g0.w + g1.x + g1.y + g1.z + g1.w;
    __builtin_nontemporal_store(o0, an + 2 * j);
    __builtin_nontemporal_store(o1, an + 2 * j + 1);
    __builtin_nontemporal_store(g0, af + 2 * j);
    __builtin_nontemporal_store(g1, af + 2 * j + 1);
    u16x8 hb;
    hb[0] = f2b(g0.x); hb[1] = f2b(g0.y); hb[2] = f2b(g0.z); hb[3] = f2b(g0.w);
    hb[4] = f2b(g1.x); hb[5] = f2b(g1.y); hb[6] = f2b(g1.z); hb[7] = f2b(g1.w);
    __builtin_nontemporal_store(hb, (u16x8*)(ab + 8 * j));
  }
  s = wave_sum(s);
  __shared__ float sm[4];
  if ((t & 63) == 0) sm[t >> 6] = s;
  __syncthreads();
  if (t == 0) {
    const float tot = sm[0] + sm[1] + sm[2] + sm[3];
    dinv2f[row] = tot > 0.f ? 1.0f / sqrtf(tot) : 0.0f;
  }
}

// ---------------------------------------------------------------- GEMM-A: Y1T = bf16(dinv2 (.) (input @ W1))^T
__global__ __launch_bounds__(256) void k_gA(const float* __restrict__ in,
                                            const ushort* __restrict__ W1T,
                                            const float* __restrict__ dinv2,
                                            ushort* __restrict__ Y1T) {
  const int wave = threadIdx.x >> 6, lane = threadIdx.x & 63;
  const int m0 = blockIdx.x * 32 + (wave & 1) * 16;
  const int c0 = (wave >> 1) * 64;
  const int r = lane & 15, kg = lane >> 4;
  f32x4 acc[4];
  #pragma unroll
  for (int i = 0; i < 4; ++i) acc[i] = f32x4{0.f, 0.f, 0.f, 0.f};
  const float* a_ptr = in + (size_t)(m0 + r) * FF + kg * 8;
  const ushort* b_ptr = W1T + (size_t)(c0 + r) * FF + kg * 8;
  #pragma unroll 2
  for (int k = 0; k < FF; k += 32) {
    const float4 f0 = *(const float4*)(a_ptr + k);
    const float4 f1 = *(const float4*)(a_ptr + k + 4);
    bf16x8 av;
    av[0] = (short)f2b(f0.x); av[1] = (short)f2b(f0.y);
    av[2] = (short)f2b(f0.z); av[3] = (short)f2b(f0.w);
    av[4] = (short)f2b(f1.x); av[5] = (short)f2b(f1.y);
    av[6] = (short)f2b(f1.z); av[7] = (short)f2b(f1.w);
    #pragma unroll
    for (int nb = 0; nb < 4; ++nb) {
      const bf16x8 bv = *(const bf16x8*)(b_ptr + (size_t)nb * 16 * FF + k);
      acc[nb] = __builtin_amdgcn_mfma_f32_16x16x32_bf16(av, bv, acc[nb], 0, 0, 0);
    }
  }
  const int mb = m0 + kg * 4;
  const float4 dv = *(const float4*)(dinv2 + mb);
  #pragma unroll
  for (int nb = 0; nb < 4; ++nb) {
    const int c = c0 + nb * 16 + r;
    u16x4 hb;
    hb.x = f2b(acc[nb][0] * dv.x); hb.y = f2b(acc[nb][1] * dv.y);
    hb.z = f2b(acc[nb][2] * dv.z); hb.w = f2b(acc[nb][3] * dv.w);
    *(u16x4*)(Y1T + (size_t)c * NN + mb) = hb;
  }
}

// ---------------------------------------------------------------- GEMM-B: P[z] = AFINB @ Y1T^T, 32x128 tiles, split-K
template <int SPLITS>
__global__ __launch_bounds__(256) void k_gB(const ushort* __restrict__ A,
                                            const ushort* __restrict__ BT,
                                            float* __restrict__ P) {
  const int wave = threadIdx.x >> 6, lane = threadIdx.x & 63;
  const int m0 = blockIdx.x * 32 + (wave & 1) * 16;
  const int c0 = (wave >> 1) * 64;
  const int klen = NN / SPLITS;
  const int kbeg = blockIdx.z * klen;
  const int r = lane & 15, kg = lane >> 4;
  f32x4 acc[4];
  #pragma unroll
  for (int i = 0; i < 4; ++i) acc[i] = f32x4{0.f, 0.f, 0.f, 0.f};
  const ushort* a_ptr = A + (size_t)(m0 + r) * NN + kbeg + kg * 8;
  const ushort* b_ptr = BT + (size_t)(c0 + r) * NN + kbeg + kg * 8;
  #pragma unroll 4
  for (int k = 0; k < klen; k += 32) {
    const bf16x8 av = *(const bf16x8*)(a_ptr + k);
    #pragma unroll
    for (int nb = 0; nb < 4; ++nb) {
      const bf16x8 bv = *(const bf16x8*)(b_ptr + (size_t)nb * 16 * NN + k);
      acc[nb] = __builtin_amdgcn_mfma_f32_16x16x32_bf16(av, bv, acc[nb], 0, 0, 0);
    }
  }
  float* Pz = P + (size_t)blockIdx.z * NN * HH;
  #pragma unroll
  for (int nb = 0; nb < 4; ++nb)
    #pragma unroll
    for (int i = 0; i < 4; ++i)
      Pz[(size_t)(m0 + kg * 4 + i) * HH + c0 + nb * 16 + r] = acc[nb][i];
}

// ---------------------------------------------------------------- GEMM-C: Y2T = bf16(dinv2 (.) (XRELU @ W2))^T
__global__ __launch_bounds__(256) void k_gC(const ushort* __restrict__ XR,
                                            const ushort* __restrict__ W2T,
                                            const float* __restrict__ dinv2,
                                            ushort* __restrict__ Y2T) {
  const int wave = threadIdx.x >> 6, lane = threadIdx.x & 63;
  const int mw = blockIdx.x * 64 + wave * 16;
  const int r = lane & 15, kg = lane >> 4;
  f32x4 acc = f32x4{0.f, 0.f, 0.f, 0.f};
  const ushort* a_ptr = XR + (size_t)(mw + r) * HH + kg * 8;
  const ushort* b_ptr = W2T + (size_t)r * HH + kg * 8;
  #pragma unroll
  for (int k = 0; k < HH; k += 32) {
    const bf16x8 av = *(const bf16x8*)(a_ptr + k);
    const bf16x8 bv = *(const bf16x8*)(b_ptr + k);
    acc = __builtin_amdgcn_mfma_f32_16x16x32_bf16(av, bv, acc, 0, 0, 0);
  }
  const int mb = mw + kg * 4;
  const float4 dv = *(const float4*)(dinv2 + mb);
  u16x4 hb;
  hb.x = f2b(acc[0] * dv.x); hb.y = f2b(acc[1] * dv.y);
  hb.z = f2b(acc[2] * dv.z); hb.w = f2b(acc[3] * dv.w);
  *(u16x4*)(Y2T + (size_t)r * NN + mb) = hb;
}

// ---------------------------------------------------------------- GEMM-D: P[z] = AFINB @ Y2T^T, 16-row waves, split-K
template <int SPLITS>
__global__ __launch_bounds__(256) void k_gD(const ushort* __restrict__ A,
                                            const ushort* __restrict__ BT,
                                            float* __restrict__ P) {
  const int wave = threadIdx.x >> 6, lane = threadIdx.x & 63;
  const int m0 = blockIdx.x * 64 + wave * 16;
  const int klen = NN / SPLITS;
  const int kbeg = blockIdx.z * klen;
  const int r = lane & 15, kg = lane >> 4;
  f32x4 acc = f32x4{0.f, 0.f, 0.f, 0.f};
  const ushort* a_ptr = A + (size_t)(m0 + r) * NN + kbeg + kg * 8;
  const ushort* b_ptr = BT + (size_t)r * NN + kbeg + kg * 8;
  #pragma unroll 4
  for (int k = 0; k < klen; k += 32) {
    const bf16x8 av = *(const bf16x8*)(a_ptr + k);
    const bf16x8 bv = *(const bf16x8*)(b_ptr + k);
    acc = __builtin_amdgcn_mfma_f32_16x16x32_bf16(av, bv, acc, 0, 0, 0);
  }
  float* Pz = P + (size_t)blockIdx.z * NN * CCC;
  #pragma unroll
  for (int i = 0; i < 4; ++i)
    Pz[(size_t)(m0 + kg * 4 + i) * CCC + r] = acc[i];
}

// ---------------------------------------------------------------- split-K reduce + epilogue + optional bf16 emit
// MODE: 3 = relu(v*rs+bias) ; 4 = v*rs+bias.  EMIT: 0 none, 2 row-major bf16
template <int MODE, int EMIT>
__global__ __launch_bounds__(256) void k_reduce(const float* __restrict__ P,
                                                float* __restrict__ C,
                                                const float* __restrict__ rs,
                                                const float* __restrict__ bias,
                                                int M, int NC, int S,
                                                ushort* __restrict__ bt) {
  const size_t idx = (size_t)blockIdx.x * 256 + threadIdx.x;
  const size_t tot = (size_t)M * NC;
  float s = 0.f;
  for (int p = 0; p < S; ++p) s += P[p * tot + idx];
  const int r = (int)(idx / NC), c = (int)(idx % NC);
  float v = s * rs[r] + bias[c];
  if constexpr (MODE == 3) v = v > 0.f ? v : 0.f;
  if (C) C[idx] = v;
  if constexpr (EMIT == 2) bt[idx] = f2b(v);
}

// ---------------------------------------------------------------- launcher
extern "C" void kernel_launch(void* const* d_in, const int* in_sizes, int n_in,
                              void* d_out, int out_size, void* d_ws, size_t ws_size,
                              hipStream_t stream) {
  const float* input = (const float*)d_in[0];
  const float* Adj   = (const float*)d_in[1];
  const float* unc   = (const float*)d_in[2];
  const float* w1    = (const float*)d_in[3];
  const float* w2    = (const float*)d_in[4];
  const float* delta = (const float*)d_in[5];
  const float* W1    = (const float*)d_in[6];
  const float* b1    = (const float*)d_in[7];
  const float* W2    = (const float*)d_in[8];
  const float* b2    = (const float*)d_in[9];

  float* xout = (float*)d_out;
  float* anew = xout + (size_t)NN * CCC;
  float* afin = anew + (size_t)NN * NN;

  float* w = (float*)d_ws;
  size_t o = 0;
  float* DINV  = w + o; o += NN;
  float* DSQ   = w + o; o += NN;
  float* EARR  = w + o; o += NN;
  float* DINV2 = w + o; o += NN;
  int*   FLAG  = (int*)(w + o);
  int*   CNT   = FLAG + 16; o += NN;
  // union region: gated scratch chain OR bf16 A_final sidecar (chain dead by then)
  float* REGION = w + o; o += (size_t)NN * NN / 2;          // NN*NN ushorts
  float* X1   = REGION;
  float* X2   = X1 + (size_t)NN * FF;
  float* EMBP = X2 + (size_t)NN * FF;
  float* EMBN = EMBP + (size_t)NN * FF;
  float* VALS = EMBN + (size_t)NN * FF;
  int*   IDX  = (int*)(VALS + (size_t)NN * KTOP);
  ushort* AFINB = (ushort*)REGION;
  ushort* Y1T    = (ushort*)(w + o); o += (size_t)NN * HH / 2;    // [128][6144]
  ushort* XRELUB = (ushort*)(w + o); o += (size_t)NN * HH / 2;    // [6144][128]
  ushort* Y2T    = (ushort*)(w + o); o += (size_t)NN * CCC / 2;   // [16][6144]
  ushort* W1T    = (ushort*)(w + o); o += (size_t)FF * HH / 2;    // [128][512]
  ushort* W2T    = (ushort*)(w + o); o += (size_t)HH * CCC / 2 + 64;
  float* PK      = w + o; o += (size_t)4 * NN * HH;               // split-K partials (12.6 MB)

  // 1. flag + e + weight transposes + barrier-counter reset
  k_flag_prep<<<257, 256, 0, stream>>>(unc, delta, EARR, FLAG, CNT, W1, W2, W1T, W2T);

  // 2. gated graph-revision chain (single dispatch; immediate exit when gate==0)
  k_gated_chain<<<GCB, 256, 0, stream>>>(Adj, input, w1, w2, DINV, DSQ, X1, X2, EMBP, EMBN,
                                         afin, anew, VALS, IDX, CNT, FLAG);

  // 3. mask, fuse with Adj, row sums of A_final, bf16 sidecar (always)
  k_mask_final<<<NN, 256, 0, stream>>>(anew, Adj, EARR, delta, afin, AFINB, DINV2, FLAG);

  // 4-9. task GCN, all-MFMA
  k_gA<<<192, 256, 0, stream>>>(input, W1T, DINV2, Y1T);
  k_gB<4><<<dim3(192, 1, 4), 256, 0, stream>>>(AFINB, Y1T, PK);
  k_reduce<3, 2><<<(NN * HH) / 256, 256, 0, stream>>>(PK, nullptr, DINV2, b1, NN, HH, 4, XRELUB);
  k_gC<<<96, 256, 0, stream>>>(XRELUB, W2T, DINV2, Y2T);
  k_gD<16><<<dim3(96, 1, 16), 256, 0, stream>>>(AFINB, Y2T, PK);
  k_reduce<4, 0><<<(NN * CCC) / 256, 256, 0, stream>>>(PK, xout, DINV2, b2, NN, CCC, 16, nullptr);
}

// Round 8
// 236.940 us; speedup vs baseline: 1.1222x; 1.1222x over previous
//
#include <hip/hip_runtime.h>
#include <cstddef>
#include <cstdint>

#define NN 6144
#define FF 512
#define HH 128
#define CCC 16
#define KTOP 50
#define GCB 256   // gated-chain blocks (<=256 -> co-resident guaranteed)

typedef __attribute__((ext_vector_type(8))) short bf16x8;
typedef __attribute__((ext_vector_type(4))) float f32x4;
typedef __attribute__((ext_vector_type(4))) ushort u16x4;

// ---------------------------------------------------------------- helpers
__device__ __forceinline__ float wave_sum(float v) {
  #pragma unroll
  for (int o = 32; o; o >>= 1) v += __shfl_down(v, o);
  return v;
}

__device__ __forceinline__ ushort f2b(float x) {   // fp32 -> bf16 RNE
  union { float f; uint32_t u; } v; v.f = x;
  const uint32_t r = v.u + 0x7FFFu + ((v.u >> 16) & 1u);
  return (ushort)(r >> 16);
}

// ---------------------------------------------------------------- flag + e + weight transposes + zero barrier counters
__global__ __launch_bounds__(256) void k_flag_prep(const float* __restrict__ u,
                                                   const float* __restrict__ delta,
                                                   float* __restrict__ e,
                                                   int* __restrict__ flag,
                                                   int* __restrict__ cnt,
                                                   const float* __restrict__ W1,
                                                   const float* __restrict__ W2,
                                                   ushort* __restrict__ W1T,
                                                   ushort* __restrict__ W2T) {
  const int b = blockIdx.x, t = threadIdx.x;
  if (b < 256) {                       // weight transposes: FF*HH = 65536 = 256*256
    const int idx = b * 256 + t;
    const int rr = idx >> 7, cc = idx & 127;
    W1T[(size_t)cc * FF + rr] = f2b(W1[idx]);
    if (idx < HH * CCC) {
      const int r2 = idx >> 4, c2 = idx & 15;
      W2T[(size_t)c2 * HH + r2] = f2b(W2[idx]);
    }
    return;
  }
  // flag block
  if (t < 8) cnt[t] = 0;
  float emax = -1e30f, dmin = 1e30f;
  for (int j = t; j < NN; j += 256) {
    float ev = expf(-u[j]);
    e[j] = ev;
    emax = fmaxf(emax, ev);
    dmin = fminf(dmin, delta[j]);
  }
  #pragma unroll
  for (int o = 32; o; o >>= 1) {
    emax = fmaxf(emax, __shfl_down(emax, o));
    dmin = fminf(dmin, __shfl_down(dmin, o));
  }
  __shared__ float sm[4], sn[4];
  if ((t & 63) == 0) { sm[t >> 6] = emax; sn[t >> 6] = dmin; }
  __syncthreads();
  if (t == 0) {
    emax = fmaxf(fmaxf(sm[0], sm[1]), fmaxf(sm[2], sm[3]));
    dmin = fminf(fminf(sn[0], sn[1]), fminf(sn[2], sn[3]));
    flag[0] = (emax >= dmin || dmin <= 0.0f) ? 1 : 0;
  }
}

// ---------------------------------------------------------------- gated chain: ONE dispatch, software phase barriers.
__device__ __forceinline__ void gbar(int* cnt, int phase) {
  __syncthreads();
  if (threadIdx.x == 0) {
    __threadfence();
    atomicAdd(&cnt[phase], 1);
    while (atomicAdd(&cnt[phase], 0) < GCB) { __builtin_amdgcn_s_sleep(8); }
    __threadfence();
  }
  __syncthreads();
}

__global__ __launch_bounds__(256) void k_gated_chain(const float* __restrict__ Adj,
                                                     const float* __restrict__ in,
                                                     const float* __restrict__ w1,
                                                     const float* __restrict__ w2,
                                                     float* __restrict__ dinv,
                                                     float* __restrict__ dsq,
                                                     float* __restrict__ X1,
                                                     float* __restrict__ X2,
                                                     float* __restrict__ EMBP,
                                                     float* __restrict__ EMBN,
                                                     float* __restrict__ afin,   // sim scratch
                                                     float* __restrict__ anew,
                                                     float* __restrict__ VALS,
                                                     int* __restrict__ IDX,
                                                     int* __restrict__ cnt,
                                                     const int* __restrict__ gate) {
  if (gate[0] == 0) return;
  const int t = threadIdx.x, bid = blockIdx.x;
  __shared__ union {
    struct { float As[64][33]; float Xs[32][128]; } g;
    struct { float Ui[64][33]; float Uj[64][33]; } s;
    struct { float sv[NN]; } k;
  } u;
  __shared__ float sm[4];
  __shared__ float fsh;
  __shared__ int bj4[4];
  __shared__ float bw[4];

  // P0: row sums of Adj + prescale input
  for (int row = bid; row < NN; row += GCB) {
    const float4* Ar = (const float4*)(Adj + (size_t)row * NN);
    float s = 0.f;
    for (int j = t; j < NN / 4; j += 256) {
      float4 v = Ar[j];
      s += v.x + v.y + v.z + v.w;
    }
    s = wave_sum(s);
    if ((t & 63) == 0) sm[t >> 6] = s;
    __syncthreads();
    if (t == 0) {
      float tot = sm[0] + sm[1] + sm[2] + sm[3];
      float dv = tot > 0.f ? 1.0f / sqrtf(tot) : 0.0f;
      dinv[row] = dv; dsq[row] = dv * dv; fsh = dv;
    }
    __syncthreads();
    const float d = fsh;
    if (t < FF / 4) {
      float4 v = ((const float4*)(in + (size_t)row * FF))[t];
      float4 w = ((const float4*)w1)[t];
      v.x *= d * w.x; v.y *= d * w.y; v.z *= d * w.z; v.w *= d * w.w;
      ((float4*)(X1 + (size_t)row * FF))[t] = v;
    }
    __syncthreads();
  }
  gbar(cnt, 0);

  // P1/P2: two fp32 GEMMs (A=Adj [NN][NN], X [NN][FF], BN=128 tiles)
  const int tx = t & 15, ty = t >> 4;
  for (int pass = 0; pass < 2; ++pass) {
    const float* Xsrc = pass == 0 ? X1 : X2;
    float* Cdst = pass == 0 ? X2 : EMBP;
    for (int tile = bid; tile < (NN / 64) * (FF / 128); tile += GCB) {
      const int row0 = (tile / 4) * 64, col0 = (tile % 4) * 128;
      float acc[4][8];
      #pragma unroll
      for (int i = 0; i < 4; ++i)
        #pragma unroll
        for (int j = 0; j < 8; ++j) acc[i][j] = 0.f;
      for (int k0 = 0; k0 < NN; k0 += 32) {
        #pragma unroll
        for (int s = t; s < 512; s += 256) {
          const int r = s >> 3, q = s & 7;
          float4 v = *(const float4*)(Adj + (size_t)(row0 + r) * NN + k0 + q * 4);
          u.g.As[r][q * 4 + 0] = v.x; u.g.As[r][q * 4 + 1] = v.y;
          u.g.As[r][q * 4 + 2] = v.z; u.g.As[r][q * 4 + 3] = v.w;
        }
        for (int s = t; s < 32 * 32; s += 256) {
          const int r = s >> 5, q = s & 31;
          *(float4*)&u.g.Xs[r][q * 4] = *(const float4*)(Xsrc + (size_t)(k0 + r) * FF + col0 + q * 4);
        }
        __syncthreads();
        #pragma unroll
        for (int kk = 0; kk < 32; ++kk) {
          float a[4];
          #pragma unroll
          for (int i = 0; i < 4; ++i) a[i] = u.g.As[ty * 4 + i][kk];
          float4 x0 = *(float4*)&u.g.Xs[kk][tx * 8];
          float4 x1 = *(float4*)&u.g.Xs[kk][tx * 8 + 4];
          #pragma unroll
          for (int i = 0; i < 4; ++i) {
            acc[i][0] += a[i] * x0.x; acc[i][1] += a[i] * x0.y;
            acc[i][2] += a[i] * x0.z; acc[i][3] += a[i] * x0.w;
            acc[i][4] += a[i] * x1.x; acc[i][5] += a[i] * x1.y;
            acc[i][6] += a[i] * x1.z; acc[i][7] += a[i] * x1.w;
          }
        }
        __syncthreads();
      }
      #pragma unroll
      for (int i = 0; i < 4; ++i)
        #pragma unroll
        for (int j = 0; j < 8; ++j) {
          const int r = row0 + ty * 4 + i, c = col0 + tx * 8 + j;
          float v = acc[i][j];
          if (pass == 0) v *= dsq[r] * w2[c];
          Cdst[(size_t)r * FF + c] = v;
        }
    }
    gbar(cnt, pass + 1);
  }

  // P3: row-normalize embeddings
  for (int row = bid; row < NN; row += GCB) {
    const float d = dinv[row];
    const float v0 = EMBP[(size_t)row * FF + t] * d;
    const float v1 = EMBP[(size_t)row * FF + 256 + t] * d;
    float ss = wave_sum(v0 * v0 + v1 * v1);
    if ((t & 63) == 0) sm[t >> 6] = ss;
    __syncthreads();
    if (t == 0) {
      const float nrm = sqrtf(sm[0] + sm[1] + sm[2] + sm[3]);
      fsh = 1.0f / fmaxf(nrm, 1e-12f);
    }
    __syncthreads();
    const float inv = fsh;
    EMBN[(size_t)row * FF + t] = v0 * inv;
    EMBN[(size_t)row * FF + 256 + t] = v1 * inv;
    __syncthreads();
  }
  gbar(cnt, 3);

  // P4: sim = U U^T (64x64 tiles) into afin scratch; also zero anew
  for (size_t i = (size_t)bid * 256 + t; i < (size_t)NN * NN / 4; i += (size_t)GCB * 256)
    ((f32x4*)anew)[i] = f32x4{0.f, 0.f, 0.f, 0.f};
  for (int tile = bid; tile < 96 * 96; tile += GCB) {
    const int bi = (tile / 96) * 64, bj = (tile % 96) * 64;
    float acc[4][4];
    #pragma unroll
    for (int i = 0; i < 4; ++i)
      #pragma unroll
      for (int j = 0; j < 4; ++j) acc[i][j] = 0.f;
    for (int k0 = 0; k0 < FF; k0 += 32) {
      #pragma unroll
      for (int s = t; s < 512; s += 256) {
        const int r = s >> 3, q = s & 7;
        float4 v = *(const float4*)(EMBN + (size_t)(bi + r) * FF + k0 + q * 4);
        u.s.Ui[r][q * 4 + 0] = v.x; u.s.Ui[r][q * 4 + 1] = v.y;
        u.s.Ui[r][q * 4 + 2] = v.z; u.s.Ui[r][q * 4 + 3] = v.w;
        float4 w = *(const float4*)(EMBN + (size_t)(bj + r) * FF + k0 + q * 4);
        u.s.Uj[r][q * 4 + 0] = w.x; u.s.Uj[r][q * 4 + 1] = w.y;
        u.s.Uj[r][q * 4 + 2] = w.z; u.s.Uj[r][q * 4 + 3] = w.w;
      }
      __syncthreads();
      #pragma unroll
      for (int kk = 0; kk < 32; ++kk) {
        float a[4], b[4];
        #pragma unroll
        for (int i = 0; i < 4; ++i) a[i] = u.s.Ui[ty * 4 + i][kk];
        #pragma unroll
        for (int j = 0; j < 4; ++j) b[j] = u.s.Uj[tx * 4 + j][kk];
        #pragma unroll
        for (int i = 0; i < 4; ++i)
          #pragma unroll
          for (int j = 0; j < 4; ++j) acc[i][j] += a[i] * b[j];
      }
      __syncthreads();
    }
    #pragma unroll
    for (int i = 0; i < 4; ++i)
      #pragma unroll
      for (int j = 0; j < 4; ++j)
        afin[(size_t)(bi + ty * 4 + i) * NN + bj + tx * 4 + j] = acc[i][j];
  }
  gbar(cnt, 4);

  // P5: top-50 per row
  for (int row = bid; row < NN; row += GCB) {
    const float* sr = afin + (size_t)row * NN;
    for (int j = t; j < NN; j += 256) u.k.sv[j] = sr[j];
    __syncthreads();
    for (int it = 0; it < KTOP; ++it) {
      float bv = -3.4e38f; int bj = NN;
      for (int j = t; j < NN; j += 256) {
        const float v = u.k.sv[j];
        if (v > bv || (v == bv && j < bj)) { bv = v; bj = j; }
      }
      #pragma unroll
      for (int o = 32; o; o >>= 1) {
        const float ov = __shfl_down(bv, o);
        const int oj = __shfl_down(bj, o);
        if (ov > bv || (ov == bv && oj < bj)) { bv = ov; bj = oj; }
      }
      if ((t & 63) == 0) { bw[t >> 6] = bv; bj4[t >> 6] = bj; }
      __syncthreads();
      if (t == 0) {
        #pragma unroll
        for (int q = 1; q < 4; ++q)
          if (bw[q] > bv || (bw[q] == bv && bj4[q] < bj)) { bv = bw[q]; bj = bj4[q]; }
        VALS[row * KTOP + it] = bv;
        IDX[row * KTOP + it] = bj;
        u.k.sv[bj] = -3.4e38f;
      }
      __syncthreads();
    }
  }
  gbar(cnt, 5);

  // P6: scatter-symmetrize
  for (int tid = bid * 256 + t; tid < NN * KTOP; tid += GCB * 256) {
    const int i = tid / KTOP;
    const float v = VALS[tid] * 0.5f;
    const int j = IDX[tid];
    atomicAdd(anew + (size_t)i * NN + j, v);
    atomicAdd(anew + (size_t)j * NN + i, v);
  }
}

// ---------------------------------------------------------------- mask + fuse + row sums + bf16 sidecar (always)
__device__ __forceinline__ float maskval(float a, float ev, float di, float m0) {
  if (a > 0.0f) {
    const float w = 2.0f / (1.0f + expf(di - ev));
    return (w >= 1.0f) ? a * w : 0.0f;
  }
  return a * m0;
}

__global__ __launch_bounds__(256) void k_mask_final(float* __restrict__ anew,
                                                    const float* __restrict__ adj,
                                                    const float* __restrict__ e,
                                                    const float* __restrict__ delta,
                                                    float* __restrict__ afin,
                                                    ushort* __restrict__ afb,
                                                    float* __restrict__ dinv2f,
                                                    const int* __restrict__ gate) {
  const int row = blockIdx.x, t = threadIdx.x;
  const bool fl = gate[0] != 0;
  const float di = delta[row];
  const float w0 = 2.0f / (1.0f + expf(di));
  const float m0 = (w0 >= 1.0f) ? w0 : 0.0f;
  const f32x4* ar = (const f32x4*)(adj + (size_t)row * NN);
  f32x4* an = (f32x4*)(anew + (size_t)row * NN);
  f32x4* af = (f32x4*)(afin + (size_t)row * NN);
  ushort* ab = afb + (size_t)row * NN;
  const f32x4* ef = (const f32x4*)e;
  float s = 0.f;
  for (int q = t; q < NN / 4; q += 256) {
    f32x4 a = fl ? an[q] : f32x4{0.f, 0.f, 0.f, 0.f};
    const f32x4 ad = __builtin_nontemporal_load(ar + q);
    const f32x4 ev = ef[q];
    f32x4 ao, fo;
    ao.x = maskval(a.x, ev.x, di, m0); fo.x = ao.x + ad.x;
    ao.y = maskval(a.y, ev.y, di, m0); fo.y = ao.y + ad.y;
    ao.z = maskval(a.z, ev.z, di, m0); fo.z = ao.z + ad.z;
    ao.w = maskval(a.w, ev.w, di, m0); fo.w = ao.w + ad.w;
    s += fo.x + fo.y + fo.z + fo.w;
    __builtin_nontemporal_store(ao, an + q);
    __builtin_nontemporal_store(fo, af + q);
    u16x4 hb;
    hb.x = f2b(fo.x); hb.y = f2b(fo.y); hb.z = f2b(fo.z); hb.w = f2b(fo.w);
    *(u16x4*)(ab + q * 4) = hb;       // regular store: keep afb L3-resident for gB/gD
  }
  s = wave_sum(s);
  __shared__ float sm[4];
  if ((t & 63) == 0) sm[t >> 6] = s;
  __syncthreads();
  if (t == 0) {
    const float tot = sm[0] + sm[1] + sm[2] + sm[3];
    dinv2f[row] = tot > 0.f ? 1.0f / sqrtf(tot) : 0.0f;
  }
}

// ---------------------------------------------------------------- GEMM-A: Y1T = bf16(dinv2 (.) (input @ W1))^T
__global__ __launch_bounds__(256) void k_gA(const float* __restrict__ in,
                                            const ushort* __restrict__ W1T,
                                            const float* __restrict__ dinv2,
                                            ushort* __restrict__ Y1T) {
  const int wave = threadIdx.x >> 6, lane = threadIdx.x & 63;
  const int m0 = blockIdx.x * 32 + (wave & 1) * 16;
  const int c0 = (wave >> 1) * 64;
  const int r = lane & 15, kg = lane >> 4;
  f32x4 acc[4];
  #pragma unroll
  for (int i = 0; i < 4; ++i) acc[i] = f32x4{0.f, 0.f, 0.f, 0.f};
  const float* a_ptr = in + (size_t)(m0 + r) * FF + kg * 8;
  const ushort* b_ptr = W1T + (size_t)(c0 + r) * FF + kg * 8;
  #pragma unroll 2
  for (int k = 0; k < FF; k += 32) {
    const float4 f0 = *(const float4*)(a_ptr + k);
    const float4 f1 = *(const float4*)(a_ptr + k + 4);
    bf16x8 av;
    av[0] = (short)f2b(f0.x); av[1] = (short)f2b(f0.y);
    av[2] = (short)f2b(f0.z); av[3] = (short)f2b(f0.w);
    av[4] = (short)f2b(f1.x); av[5] = (short)f2b(f1.y);
    av[6] = (short)f2b(f1.z); av[7] = (short)f2b(f1.w);
    #pragma unroll
    for (int nb = 0; nb < 4; ++nb) {
      const bf16x8 bv = *(const bf16x8*)(b_ptr + (size_t)nb * 16 * FF + k);
      acc[nb] = __builtin_amdgcn_mfma_f32_16x16x32_bf16(av, bv, acc[nb], 0, 0, 0);
    }
  }
  const int mb = m0 + kg * 4;
  const float4 dv = *(const float4*)(dinv2 + mb);
  #pragma unroll
  for (int nb = 0; nb < 4; ++nb) {
    const int c = c0 + nb * 16 + r;
    u16x4 hb;
    hb.x = f2b(acc[nb][0] * dv.x); hb.y = f2b(acc[nb][1] * dv.y);
    hb.z = f2b(acc[nb][2] * dv.z); hb.w = f2b(acc[nb][3] * dv.w);
    *(u16x4*)(Y1T + (size_t)c * NN + mb) = hb;
  }
}

// ---------------------------------------------------------------- GEMM-B: P[z] = AFINB @ Y1T^T, 32x128 tiles, split-K
template <int SPLITS>
__global__ __launch_bounds__(256) void k_gB(const ushort* __restrict__ A,
                                            const ushort* __restrict__ BT,
                                            float* __restrict__ P) {
  const int wave = threadIdx.x >> 6, lane = threadIdx.x & 63;
  const int m0 = blockIdx.x * 32 + (wave & 1) * 16;
  const int c0 = (wave >> 1) * 64;
  const int klen = NN / SPLITS;
  const int kbeg = blockIdx.z * klen;
  const int r = lane & 15, kg = lane >> 4;
  f32x4 acc[4];
  #pragma unroll
  for (int i = 0; i < 4; ++i) acc[i] = f32x4{0.f, 0.f, 0.f, 0.f};
  const ushort* a_ptr = A + (size_t)(m0 + r) * NN + kbeg + kg * 8;
  const ushort* b_ptr = BT + (size_t)(c0 + r) * NN + kbeg + kg * 8;
  #pragma unroll 4
  for (int k = 0; k < klen; k += 32) {
    const bf16x8 av = *(const bf16x8*)(a_ptr + k);
    #pragma unroll
    for (int nb = 0; nb < 4; ++nb) {
      const bf16x8 bv = *(const bf16x8*)(b_ptr + (size_t)nb * 16 * NN + k);
      acc[nb] = __builtin_amdgcn_mfma_f32_16x16x32_bf16(av, bv, acc[nb], 0, 0, 0);
    }
  }
  float* Pz = P + (size_t)blockIdx.z * NN * HH;
  #pragma unroll
  for (int nb = 0; nb < 4; ++nb)
    #pragma unroll
    for (int i = 0; i < 4; ++i)
      Pz[(size_t)(m0 + kg * 4 + i) * HH + c0 + nb * 16 + r] = acc[nb][i];
}

// ---------------------------------------------------------------- GEMM-C: Y2T = bf16(dinv2 (.) (XRELU @ W2))^T
__global__ __launch_bounds__(256) void k_gC(const ushort* __restrict__ XR,
                                            const ushort* __restrict__ W2T,
                                            const float* __restrict__ dinv2,
                                            ushort* __restrict__ Y2T) {
  const int wave = threadIdx.x >> 6, lane = threadIdx.x & 63;
  const int mw = blockIdx.x * 64 + wave * 16;
  const int r = lane & 15, kg = lane >> 4;
  f32x4 acc = f32x4{0.f, 0.f, 0.f, 0.f};
  const ushort* a_ptr = XR + (size_t)(mw + r) * HH + kg * 8;
  const ushort* b_ptr = W2T + (size_t)r * HH + kg * 8;
  #pragma unroll
  for (int k = 0; k < HH; k += 32) {
    const bf16x8 av = *(const bf16x8*)(a_ptr + k);
    const bf16x8 bv = *(const bf16x8*)(b_ptr + k);
    acc = __builtin_amdgcn_mfma_f32_16x16x32_bf16(av, bv, acc, 0, 0, 0);
  }
  const int mb = mw + kg * 4;
  const float4 dv = *(const float4*)(dinv2 + mb);
  u16x4 hb;
  hb.x = f2b(acc[0] * dv.x); hb.y = f2b(acc[1] * dv.y);
  hb.z = f2b(acc[2] * dv.z); hb.w = f2b(acc[3] * dv.w);
  *(u16x4*)(Y2T + (size_t)r * NN + mb) = hb;
}

// ---------------------------------------------------------------- GEMM-D: P[z] = AFINB @ Y2T^T, 16-row waves, split-K
template <int SPLITS>
__global__ __launch_bounds__(256) void k_gD(const ushort* __restrict__ A,
                                            const ushort* __restrict__ BT,
                                            float* __restrict__ P) {
  const int wave = threadIdx.x >> 6, lane = threadIdx.x & 63;
  const int m0 = blockIdx.x * 64 + wave * 16;
  const int klen = NN / SPLITS;
  const int kbeg = blockIdx.z * klen;
  const int r = lane & 15, kg = lane >> 4;
  f32x4 acc = f32x4{0.f, 0.f, 0.f, 0.f};
  const ushort* a_ptr = A + (size_t)(m0 + r) * NN + kbeg + kg * 8;
  const ushort* b_ptr = BT + (size_t)r * NN + kbeg + kg * 8;
  #pragma unroll 4
  for (int k = 0; k < klen; k += 32) {
    const bf16x8 av = *(const bf16x8*)(a_ptr + k);
    const bf16x8 bv = *(const bf16x8*)(b_ptr + k);
    acc = __builtin_amdgcn_mfma_f32_16x16x32_bf16(av, bv, acc, 0, 0, 0);
  }
  float* Pz = P + (size_t)blockIdx.z * NN * CCC;
  #pragma unroll
  for (int i = 0; i < 4; ++i)
    Pz[(size_t)(m0 + kg * 4 + i) * CCC + r] = acc[i];
}

// ---------------------------------------------------------------- split-K reduce + epilogue + optional bf16 emit
// MODE: 3 = relu(v*rs+bias) ; 4 = v*rs+bias.  EMIT: 0 none, 2 row-major bf16
template <int MODE, int EMIT>
__global__ __launch_bounds__(256) void k_reduce(const float* __restrict__ P,
                                                float* __restrict__ C,
                                                const float* __restrict__ rs,
                                                const float* __restrict__ bias,
                                                int M, int NC, int S,
                                                ushort* __restrict__ bt) {
  const size_t idx = (size_t)blockIdx.x * 256 + threadIdx.x;
  const size_t tot = (size_t)M * NC;
  float s = 0.f;
  for (int p = 0; p < S; ++p) s += P[p * tot + idx];
  const int r = (int)(idx / NC), c = (int)(idx % NC);
  float v = s * rs[r] + bias[c];
  if constexpr (MODE == 3) v = v > 0.f ? v : 0.f;
  if (C) C[idx] = v;
  if constexpr (EMIT == 2) bt[idx] = f2b(v);
}

// ---------------------------------------------------------------- launcher
extern "C" void kernel_launch(void* const* d_in, const int* in_sizes, int n_in,
                              void* d_out, int out_size, void* d_ws, size_t ws_size,
                              hipStream_t stream) {
  const float* input = (const float*)d_in[0];
  const float* Adj   = (const float*)d_in[1];
  const float* unc   = (const float*)d_in[2];
  const float* w1    = (const float*)d_in[3];
  const float* w2    = (const float*)d_in[4];
  const float* delta = (const float*)d_in[5];
  const float* W1    = (const float*)d_in[6];
  const float* b1    = (const float*)d_in[7];
  const float* W2    = (const float*)d_in[8];
  const float* b2    = (const float*)d_in[9];

  float* xout = (float*)d_out;
  float* anew = xout + (size_t)NN * CCC;
  float* afin = anew + (size_t)NN * NN;

  float* w = (float*)d_ws;
  size_t o = 0;
  float* DINV  = w + o; o += NN;
  float* DSQ   = w + o; o += NN;
  float* EARR  = w + o; o += NN;
  float* DINV2 = w + o; o += NN;
  int*   FLAG  = (int*)(w + o);
  int*   CNT   = FLAG + 16; o += NN;
  // union region: gated scratch chain OR bf16 A_final sidecar (chain dead by then)
  float* REGION = w + o; o += (size_t)NN * NN / 2;          // NN*NN ushorts
  float* X1   = REGION;
  float* X2   = X1 + (size_t)NN * FF;
  float* EMBP = X2 + (size_t)NN * FF;
  float* EMBN = EMBP + (size_t)NN * FF;
  float* VALS = EMBN + (size_t)NN * FF;
  int*   IDX  = (int*)(VALS + (size_t)NN * KTOP);
  ushort* AFINB = (ushort*)REGION;
  ushort* Y1T    = (ushort*)(w + o); o += (size_t)NN * HH / 2;    // [128][6144]
  ushort* XRELUB = (ushort*)(w + o); o += (size_t)NN * HH / 2;    // [6144][128]
  ushort* Y2T    = (ushort*)(w + o); o += (size_t)NN * CCC / 2;   // [16][6144]
  ushort* W1T    = (ushort*)(w + o); o += (size_t)FF * HH / 2;    // [128][512]
  ushort* W2T    = (ushort*)(w + o); o += (size_t)HH * CCC / 2 + 64;
  float* PK      = w + o; o += (size_t)4 * NN * HH;               // split-K partials (12.6 MB)

  // 1. flag + e + weight transposes + barrier-counter reset
  k_flag_prep<<<257, 256, 0, stream>>>(unc, delta, EARR, FLAG, CNT, W1, W2, W1T, W2T);

  // 2. gated graph-revision chain (single dispatch; immediate exit when gate==0)
  k_gated_chain<<<GCB, 256, 0, stream>>>(Adj, input, w1, w2, DINV, DSQ, X1, X2, EMBP, EMBN,
                                         afin, anew, VALS, IDX, CNT, FLAG);

  // 3. mask, fuse with Adj, row sums of A_final, bf16 sidecar (always)
  k_mask_final<<<NN, 256, 0, stream>>>(anew, Adj, EARR, delta, afin, AFINB, DINV2, FLAG);

  // 4-9. task GCN, all-MFMA
  k_gA<<<192, 256, 0, stream>>>(input, W1T, DINV2, Y1T);
  k_gB<4><<<dim3(192, 1, 4), 256, 0, stream>>>(AFINB, Y1T, PK);
  k_reduce<3, 2><<<(NN * HH) / 256, 256, 0, stream>>>(PK, nullptr, DINV2, b1, NN, HH, 4, XRELUB);
  k_gC<<<96, 256, 0, stream>>>(XRELUB, W2T, DINV2, Y2T);
  k_gD<16><<<dim3(96, 1, 16), 256, 0, stream>>>(AFINB, Y2T, PK);
  k_reduce<4, 0><<<(NN * CCC) / 256, 256, 0, stream>>>(PK, xout, DINV2, b2, NN, CCC, 16, nullptr);
}

// Round 9
// 220.053 us; speedup vs baseline: 1.2083x; 1.0767x over previous
//
#include <hip/hip_runtime.h>
#include <cstddef>
#include <cstdint>

#define NN 6144
#define FF 512
#define HH 128
#define CCC 16
#define KTOP 50
#define GCB 256   // gated-chain blocks (<=256 -> co-resident guaranteed)

typedef __attribute__((ext_vector_type(8))) short bf16x8;
typedef __attribute__((ext_vector_type(4))) float f32x4;
typedef __attribute__((ext_vector_type(4))) ushort u16x4;

// ---------------------------------------------------------------- helpers
__device__ __forceinline__ float wave_sum(float v) {
  #pragma unroll
  for (int o = 32; o; o >>= 1) v += __shfl_down(v, o);
  return v;
}

__device__ __forceinline__ ushort f2b(float x) {   // fp32 -> bf16 RNE
  union { float f; uint32_t u; } v; v.f = x;
  const uint32_t r = v.u + 0x7FFFu + ((v.u >> 16) & 1u);
  return (ushort)(r >> 16);
}

// ---------------------------------------------------------------- flag + e + weight transposes + zero barrier counters
__global__ __launch_bounds__(256) void k_flag_prep(const float* __restrict__ u,
                                                   const float* __restrict__ delta,
                                                   float* __restrict__ e,
                                                   int* __restrict__ flag,
                                                   int* __restrict__ cnt,
                                                   const float* __restrict__ W1,
                                                   const float* __restrict__ W2,
                                                   ushort* __restrict__ W1T,
                                                   ushort* __restrict__ W2T) {
  const int b = blockIdx.x, t = threadIdx.x;
  if (b < 256) {                       // weight transposes: FF*HH = 65536 = 256*256
    const int idx = b * 256 + t;
    const int rr = idx >> 7, cc = idx & 127;
    W1T[(size_t)cc * FF + rr] = f2b(W1[idx]);
    if (idx < HH * CCC) {
      const int r2 = idx >> 4, c2 = idx & 15;
      W2T[(size_t)c2 * HH + r2] = f2b(W2[idx]);
    }
    return;
  }
  // flag block
  if (t < 8) cnt[t] = 0;
  float emax = -1e30f, dmin = 1e30f;
  for (int j = t; j < NN; j += 256) {
    float ev = expf(-u[j]);
    e[j] = ev;
    emax = fmaxf(emax, ev);
    dmin = fminf(dmin, delta[j]);
  }
  #pragma unroll
  for (int o = 32; o; o >>= 1) {
    emax = fmaxf(emax, __shfl_down(emax, o));
    dmin = fminf(dmin, __shfl_down(dmin, o));
  }
  __shared__ float sm[4], sn[4];
  if ((t & 63) == 0) { sm[t >> 6] = emax; sn[t >> 6] = dmin; }
  __syncthreads();
  if (t == 0) {
    emax = fmaxf(fmaxf(sm[0], sm[1]), fmaxf(sm[2], sm[3]));
    dmin = fminf(fminf(sn[0], sn[1]), fminf(sn[2], sn[3]));
    flag[0] = (emax >= dmin || dmin <= 0.0f) ? 1 : 0;
  }
}

// ---------------------------------------------------------------- gated chain: ONE dispatch, software phase barriers.
__device__ __forceinline__ void gbar(int* cnt, int phase) {
  __syncthreads();
  if (threadIdx.x == 0) {
    __threadfence();
    atomicAdd(&cnt[phase], 1);
    while (atomicAdd(&cnt[phase], 0) < GCB) { __builtin_amdgcn_s_sleep(8); }
    __threadfence();
  }
  __syncthreads();
}

__global__ __launch_bounds__(256) void k_gated_chain(const float* __restrict__ Adj,
                                                     const float* __restrict__ in,
                                                     const float* __restrict__ w1,
                                                     const float* __restrict__ w2,
                                                     float* __restrict__ dinv,
                                                     float* __restrict__ dsq,
                                                     float* __restrict__ X1,
                                                     float* __restrict__ X2,
                                                     float* __restrict__ EMBP,
                                                     float* __restrict__ EMBN,
                                                     float* __restrict__ afin,   // sim scratch
                                                     float* __restrict__ anew,
                                                     float* __restrict__ VALS,
                                                     int* __restrict__ IDX,
                                                     int* __restrict__ cnt,
                                                     const int* __restrict__ gate) {
  if (gate[0] == 0) return;
  const int t = threadIdx.x, bid = blockIdx.x;
  __shared__ union {
    struct { float As[64][33]; float Xs[32][128]; } g;
    struct { float Ui[64][33]; float Uj[64][33]; } s;
    struct { float sv[NN]; } k;
  } u;
  __shared__ float sm[4];
  __shared__ float fsh;
  __shared__ int bj4[4];
  __shared__ float bw[4];

  // P0: row sums of Adj + prescale input
  for (int row = bid; row < NN; row += GCB) {
    const float4* Ar = (const float4*)(Adj + (size_t)row * NN);
    float s = 0.f;
    for (int j = t; j < NN / 4; j += 256) {
      float4 v = Ar[j];
      s += v.x + v.y + v.z + v.w;
    }
    s = wave_sum(s);
    if ((t & 63) == 0) sm[t >> 6] = s;
    __syncthreads();
    if (t == 0) {
      float tot = sm[0] + sm[1] + sm[2] + sm[3];
      float dv = tot > 0.f ? 1.0f / sqrtf(tot) : 0.0f;
      dinv[row] = dv; dsq[row] = dv * dv; fsh = dv;
    }
    __syncthreads();
    const float d = fsh;
    if (t < FF / 4) {
      float4 v = ((const float4*)(in + (size_t)row * FF))[t];
      float4 w = ((const float4*)w1)[t];
      v.x *= d * w.x; v.y *= d * w.y; v.z *= d * w.z; v.w *= d * w.w;
      ((float4*)(X1 + (size_t)row * FF))[t] = v;
    }
    __syncthreads();
  }
  gbar(cnt, 0);

  // P1/P2: two fp32 GEMMs (A=Adj [NN][NN], X [NN][FF], BN=128 tiles)
  const int tx = t & 15, ty = t >> 4;
  for (int pass = 0; pass < 2; ++pass) {
    const float* Xsrc = pass == 0 ? X1 : X2;
    float* Cdst = pass == 0 ? X2 : EMBP;
    for (int tile = bid; tile < (NN / 64) * (FF / 128); tile += GCB) {
      const int row0 = (tile / 4) * 64, col0 = (tile % 4) * 128;
      float acc[4][8];
      #pragma unroll
      for (int i = 0; i < 4; ++i)
        #pragma unroll
        for (int j = 0; j < 8; ++j) acc[i][j] = 0.f;
      for (int k0 = 0; k0 < NN; k0 += 32) {
        #pragma unroll
        for (int s = t; s < 512; s += 256) {
          const int r = s >> 3, q = s & 7;
          float4 v = *(const float4*)(Adj + (size_t)(row0 + r) * NN + k0 + q * 4);
          u.g.As[r][q * 4 + 0] = v.x; u.g.As[r][q * 4 + 1] = v.y;
          u.g.As[r][q * 4 + 2] = v.z; u.g.As[r][q * 4 + 3] = v.w;
        }
        for (int s = t; s < 32 * 32; s += 256) {
          const int r = s >> 5, q = s & 31;
          *(float4*)&u.g.Xs[r][q * 4] = *(const float4*)(Xsrc + (size_t)(k0 + r) * FF + col0 + q * 4);
        }
        __syncthreads();
        #pragma unroll
        for (int kk = 0; kk < 32; ++kk) {
          float a[4];
          #pragma unroll
          for (int i = 0; i < 4; ++i) a[i] = u.g.As[ty * 4 + i][kk];
          float4 x0 = *(float4*)&u.g.Xs[kk][tx * 8];
          float4 x1 = *(float4*)&u.g.Xs[kk][tx * 8 + 4];
          #pragma unroll
          for (int i = 0; i < 4; ++i) {
            acc[i][0] += a[i] * x0.x; acc[i][1] += a[i] * x0.y;
            acc[i][2] += a[i] * x0.z; acc[i][3] += a[i] * x0.w;
            acc[i][4] += a[i] * x1.x; acc[i][5] += a[i] * x1.y;
            acc[i][6] += a[i] * x1.z; acc[i][7] += a[i] * x1.w;
          }
        }
        __syncthreads();
      }
      #pragma unroll
      for (int i = 0; i < 4; ++i)
        #pragma unroll
        for (int j = 0; j < 8; ++j) {
          const int r = row0 + ty * 4 + i, c = col0 + tx * 8 + j;
          float v = acc[i][j];
          if (pass == 0) v *= dsq[r] * w2[c];
          Cdst[(size_t)r * FF + c] = v;
        }
    }
    gbar(cnt, pass + 1);
  }

  // P3: row-normalize embeddings
  for (int row = bid; row < NN; row += GCB) {
    const float d = dinv[row];
    const float v0 = EMBP[(size_t)row * FF + t] * d;
    const float v1 = EMBP[(size_t)row * FF + 256 + t] * d;
    float ss = wave_sum(v0 * v0 + v1 * v1);
    if ((t & 63) == 0) sm[t >> 6] = ss;
    __syncthreads();
    if (t == 0) {
      const float nrm = sqrtf(sm[0] + sm[1] + sm[2] + sm[3]);
      fsh = 1.0f / fmaxf(nrm, 1e-12f);
    }
    __syncthreads();
    const float inv = fsh;
    EMBN[(size_t)row * FF + t] = v0 * inv;
    EMBN[(size_t)row * FF + 256 + t] = v1 * inv;
    __syncthreads();
  }
  gbar(cnt, 3);

  // P4: sim = U U^T (64x64 tiles) into afin scratch; also zero anew
  for (size_t i = (size_t)bid * 256 + t; i < (size_t)NN * NN / 4; i += (size_t)GCB * 256)
    ((f32x4*)anew)[i] = f32x4{0.f, 0.f, 0.f, 0.f};
  for (int tile = bid; tile < 96 * 96; tile += GCB) {
    const int bi = (tile / 96) * 64, bj = (tile % 96) * 64;
    float acc[4][4];
    #pragma unroll
    for (int i = 0; i < 4; ++i)
      #pragma unroll
      for (int j = 0; j < 4; ++j) acc[i][j] = 0.f;
    for (int k0 = 0; k0 < FF; k0 += 32) {
      #pragma unroll
      for (int s = t; s < 512; s += 256) {
        const int r = s >> 3, q = s & 7;
        float4 v = *(const float4*)(EMBN + (size_t)(bi + r) * FF + k0 + q * 4);
        u.s.Ui[r][q * 4 + 0] = v.x; u.s.Ui[r][q * 4 + 1] = v.y;
        u.s.Ui[r][q * 4 + 2] = v.z; u.s.Ui[r][q * 4 + 3] = v.w;
        float4 w = *(const float4*)(EMBN + (size_t)(bj + r) * FF + k0 + q * 4);
        u.s.Uj[r][q * 4 + 0] = w.x; u.s.Uj[r][q * 4 + 1] = w.y;
        u.s.Uj[r][q * 4 + 2] = w.z; u.s.Uj[r][q * 4 + 3] = w.w;
      }
      __syncthreads();
      #pragma unroll
      for (int kk = 0; kk < 32; ++kk) {
        float a[4], b[4];
        #pragma unroll
        for (int i = 0; i < 4; ++i) a[i] = u.s.Ui[ty * 4 + i][kk];
        #pragma unroll
        for (int j = 0; j < 4; ++j) b[j] = u.s.Uj[tx * 4 + j][kk];
        #pragma unroll
        for (int i = 0; i < 4; ++i)
          #pragma unroll
          for (int j = 0; j < 4; ++j) acc[i][j] += a[i] * b[j];
      }
      __syncthreads();
    }
    #pragma unroll
    for (int i = 0; i < 4; ++i)
      #pragma unroll
      for (int j = 0; j < 4; ++j)
        afin[(size_t)(bi + ty * 4 + i) * NN + bj + tx * 4 + j] = acc[i][j];
  }
  gbar(cnt, 4);

  // P5: top-50 per row
  for (int row = bid; row < NN; row += GCB) {
    const float* sr = afin + (size_t)row * NN;
    for (int j = t; j < NN; j += 256) u.k.sv[j] = sr[j];
    __syncthreads();
    for (int it = 0; it < KTOP; ++it) {
      float bv = -3.4e38f; int bj = NN;
      for (int j = t; j < NN; j += 256) {
        const float v = u.k.sv[j];
        if (v > bv || (v == bv && j < bj)) { bv = v; bj = j; }
      }
      #pragma unroll
      for (int o = 32; o; o >>= 1) {
        const float ov = __shfl_down(bv, o);
        const int oj = __shfl_down(bj, o);
        if (ov > bv || (ov == bv && oj < bj)) { bv = ov; bj = oj; }
      }
      if ((t & 63) == 0) { bw[t >> 6] = bv; bj4[t >> 6] = bj; }
      __syncthreads();
      if (t == 0) {
        #pragma unroll
        for (int q = 1; q < 4; ++q)
          if (bw[q] > bv || (bw[q] == bv && bj4[q] < bj)) { bv = bw[q]; bj = bj4[q]; }
        VALS[row * KTOP + it] = bv;
        IDX[row * KTOP + it] = bj;
        u.k.sv[bj] = -3.4e38f;
      }
      __syncthreads();
    }
  }
  gbar(cnt, 5);

  // P6: scatter-symmetrize
  for (int tid = bid * 256 + t; tid < NN * KTOP; tid += GCB * 256) {
    const int i = tid / KTOP;
    const float v = VALS[tid] * 0.5f;
    const int j = IDX[tid];
    atomicAdd(anew + (size_t)i * NN + j, v);
    atomicAdd(anew + (size_t)j * NN + i, v);
  }
}

// ---------------------------------------------------------------- mask + fuse + row sums + bf16 sidecar (always)
__device__ __forceinline__ float maskval(float a, float ev, float di, float m0) {
  if (a > 0.0f) {
    const float w = 2.0f / (1.0f + expf(di - ev));
    return (w >= 1.0f) ? a * w : 0.0f;
  }
  return a * m0;
}

__global__ __launch_bounds__(256) void k_mask_final(float* __restrict__ anew,
                                                    const float* __restrict__ adj,
                                                    const float* __restrict__ e,
                                                    const float* __restrict__ delta,
                                                    float* __restrict__ afin,
                                                    ushort* __restrict__ afb,
                                                    float* __restrict__ dinv2f,
                                                    const int* __restrict__ gate) {
  const int row = blockIdx.x, t = threadIdx.x;
  const bool fl = gate[0] != 0;
  const f32x4* ar = (const f32x4*)(adj + (size_t)row * NN);
  f32x4* af = (f32x4*)(afin + (size_t)row * NN);
  ushort* ab = afb + (size_t)row * NN;
  float s = 0.f;
  if (!fl) {
    // gate==0: A_new=0 (pre-memset), A_final = Adj. Pure stream: copy+cast+sum.
    for (int q = t; q < NN / 4; q += 256) {
      const f32x4 ad = __builtin_nontemporal_load(ar + q);
      s += ad.x + ad.y + ad.z + ad.w;
      __builtin_nontemporal_store(ad, af + q);
      u16x4 hb;
      hb.x = f2b(ad.x); hb.y = f2b(ad.y); hb.z = f2b(ad.z); hb.w = f2b(ad.w);
      *(u16x4*)(ab + q * 4) = hb;     // regular store: keep afb L3-resident for gB/gD
    }
  } else {
    const float di = delta[row];
    const float w0 = 2.0f / (1.0f + expf(di));
    const float m0 = (w0 >= 1.0f) ? w0 : 0.0f;
    f32x4* an = (f32x4*)(anew + (size_t)row * NN);
    const f32x4* ef = (const f32x4*)e;
    for (int q = t; q < NN / 4; q += 256) {
      f32x4 a = an[q];
      const f32x4 ad = __builtin_nontemporal_load(ar + q);
      const f32x4 ev = ef[q];
      f32x4 ao, fo;
      ao.x = maskval(a.x, ev.x, di, m0); fo.x = ao.x + ad.x;
      ao.y = maskval(a.y, ev.y, di, m0); fo.y = ao.y + ad.y;
      ao.z = maskval(a.z, ev.z, di, m0); fo.z = ao.z + ad.z;
      ao.w = maskval(a.w, ev.w, di, m0); fo.w = ao.w + ad.w;
      s += fo.x + fo.y + fo.z + fo.w;
      __builtin_nontemporal_store(ao, an + q);
      __builtin_nontemporal_store(fo, af + q);
      u16x4 hb;
      hb.x = f2b(fo.x); hb.y = f2b(fo.y); hb.z = f2b(fo.z); hb.w = f2b(fo.w);
      *(u16x4*)(ab + q * 4) = hb;
    }
  }
  s = wave_sum(s);
  __shared__ float sm[4];
  if ((t & 63) == 0) sm[t >> 6] = s;
  __syncthreads();
  if (t == 0) {
    const float tot = sm[0] + sm[1] + sm[2] + sm[3];
    dinv2f[row] = tot > 0.f ? 1.0f / sqrtf(tot) : 0.0f;
  }
}

// ---------------------------------------------------------------- GEMM-A: Y1T = bf16(dinv2 (.) (input @ W1))^T
__global__ __launch_bounds__(256) void k_gA(const float* __restrict__ in,
                                            const ushort* __restrict__ W1T,
                                            const float* __restrict__ dinv2,
                                            ushort* __restrict__ Y1T) {
  const int wave = threadIdx.x >> 6, lane = threadIdx.x & 63;
  const int m0 = blockIdx.x * 32 + (wave & 1) * 16;
  const int c0 = (wave >> 1) * 64;
  const int r = lane & 15, kg = lane >> 4;
  f32x4 acc[4];
  #pragma unroll
  for (int i = 0; i < 4; ++i) acc[i] = f32x4{0.f, 0.f, 0.f, 0.f};
  const float* a_ptr = in + (size_t)(m0 + r) * FF + kg * 8;
  const ushort* b_ptr = W1T + (size_t)(c0 + r) * FF + kg * 8;
  #pragma unroll 2
  for (int k = 0; k < FF; k += 32) {
    const float4 f0 = *(const float4*)(a_ptr + k);
    const float4 f1 = *(const float4*)(a_ptr + k + 4);
    bf16x8 av;
    av[0] = (short)f2b(f0.x); av[1] = (short)f2b(f0.y);
    av[2] = (short)f2b(f0.z); av[3] = (short)f2b(f0.w);
    av[4] = (short)f2b(f1.x); av[5] = (short)f2b(f1.y);
    av[6] = (short)f2b(f1.z); av[7] = (short)f2b(f1.w);
    #pragma unroll
    for (int nb = 0; nb < 4; ++nb) {
      const bf16x8 bv = *(const bf16x8*)(b_ptr + (size_t)nb * 16 * FF + k);
      acc[nb] = __builtin_amdgcn_mfma_f32_16x16x32_bf16(av, bv, acc[nb], 0, 0, 0);
    }
  }
  const int mb = m0 + kg * 4;
  const float4 dv = *(const float4*)(dinv2 + mb);
  #pragma unroll
  for (int nb = 0; nb < 4; ++nb) {
    const int c = c0 + nb * 16 + r;
    u16x4 hb;
    hb.x = f2b(acc[nb][0] * dv.x); hb.y = f2b(acc[nb][1] * dv.y);
    hb.z = f2b(acc[nb][2] * dv.z); hb.w = f2b(acc[nb][3] * dv.w);
    *(u16x4*)(Y1T + (size_t)c * NN + mb) = hb;
  }
}

// ---------------------------------------------------------------- GEMM-B: P[z] = AFINB @ Y1T^T, 32x128 tiles, split-K
template <int SPLITS>
__global__ __launch_bounds__(256) void k_gB(const ushort* __restrict__ A,
                                            const ushort* __restrict__ BT,
                                            float* __restrict__ P) {
  const int wave = threadIdx.x >> 6, lane = threadIdx.x & 63;
  const int m0 = blockIdx.x * 32 + (wave & 1) * 16;
  const int c0 = (wave >> 1) * 64;
  const int klen = NN / SPLITS;
  const int kbeg = blockIdx.z * klen;
  const int r = lane & 15, kg = lane >> 4;
  f32x4 acc[4];
  #pragma unroll
  for (int i = 0; i < 4; ++i) acc[i] = f32x4{0.f, 0.f, 0.f, 0.f};
  const ushort* a_ptr = A + (size_t)(m0 + r) * NN + kbeg + kg * 8;
  const ushort* b_ptr = BT + (size_t)(c0 + r) * NN + kbeg + kg * 8;
  #pragma unroll 4
  for (int k = 0; k < klen; k += 32) {
    const bf16x8 av = *(const bf16x8*)(a_ptr + k);
    #pragma unroll
    for (int nb = 0; nb < 4; ++nb) {
      const bf16x8 bv = *(const bf16x8*)(b_ptr + (size_t)nb * 16 * NN + k);
      acc[nb] = __builtin_amdgcn_mfma_f32_16x16x32_bf16(av, bv, acc[nb], 0, 0, 0);
    }
  }
  float* Pz = P + (size_t)blockIdx.z * NN * HH;
  #pragma unroll
  for (int nb = 0; nb < 4; ++nb)
    #pragma unroll
    for (int i = 0; i < 4; ++i)
      Pz[(size_t)(m0 + kg * 4 + i) * HH + c0 + nb * 16 + r] = acc[nb][i];
}

// ---------------------------------------------------------------- GEMM-C: Y2T = bf16(dinv2 (.) (XRELU @ W2))^T
__global__ __launch_bounds__(256) void k_gC(const ushort* __restrict__ XR,
                                            const ushort* __restrict__ W2T,
                                            const float* __restrict__ dinv2,
                                            ushort* __restrict__ Y2T) {
  const int wave = threadIdx.x >> 6, lane = threadIdx.x & 63;
  const int mw = blockIdx.x * 64 + wave * 16;
  const int r = lane & 15, kg = lane >> 4;
  f32x4 acc = f32x4{0.f, 0.f, 0.f, 0.f};
  const ushort* a_ptr = XR + (size_t)(mw + r) * HH + kg * 8;
  const ushort* b_ptr = W2T + (size_t)r * HH + kg * 8;
  #pragma unroll
  for (int k = 0; k < HH; k += 32) {
    const bf16x8 av = *(const bf16x8*)(a_ptr + k);
    const bf16x8 bv = *(const bf16x8*)(b_ptr + k);
    acc = __builtin_amdgcn_mfma_f32_16x16x32_bf16(av, bv, acc, 0, 0, 0);
  }
  const int mb = mw + kg * 4;
  const float4 dv = *(const float4*)(dinv2 + mb);
  u16x4 hb;
  hb.x = f2b(acc[0] * dv.x); hb.y = f2b(acc[1] * dv.y);
  hb.z = f2b(acc[2] * dv.z); hb.w = f2b(acc[3] * dv.w);
  *(u16x4*)(Y2T + (size_t)r * NN + mb) = hb;
}

// ---------------------------------------------------------------- GEMM-D: P[z] = AFINB @ Y2T^T, 16-row waves, split-K
template <int SPLITS>
__global__ __launch_bounds__(256) void k_gD(const ushort* __restrict__ A,
                                            const ushort* __restrict__ BT,
                                            float* __restrict__ P) {
  const int wave = threadIdx.x >> 6, lane = threadIdx.x & 63;
  const int m0 = blockIdx.x * 64 + wave * 16;
  const int klen = NN / SPLITS;
  const int kbeg = blockIdx.z * klen;
  const int r = lane & 15, kg = lane >> 4;
  f32x4 acc = f32x4{0.f, 0.f, 0.f, 0.f};
  const ushort* a_ptr = A + (size_t)(m0 + r) * NN + kbeg + kg * 8;
  const ushort* b_ptr = BT + (size_t)r * NN + kbeg + kg * 8;
  #pragma unroll 4
  for (int k = 0; k < klen; k += 32) {
    const bf16x8 av = *(const bf16x8*)(a_ptr + k);
    const bf16x8 bv = *(const bf16x8*)(b_ptr + k);
    acc = __builtin_amdgcn_mfma_f32_16x16x32_bf16(av, bv, acc, 0, 0, 0);
  }
  float* Pz = P + (size_t)blockIdx.z * NN * CCC;
  #pragma unroll
  for (int i = 0; i < 4; ++i)
    Pz[(size_t)(m0 + kg * 4 + i) * CCC + r] = acc[i];
}

// ---------------------------------------------------------------- split-K reduce + epilogue + optional bf16 emit
// MODE: 3 = relu(v*rs+bias) ; 4 = v*rs+bias.  EMIT: 0 none, 2 row-major bf16
template <int MODE, int EMIT>
__global__ __launch_bounds__(256) void k_reduce(const float* __restrict__ P,
                                                float* __restrict__ C,
                                                const float* __restrict__ rs,
                                                const float* __restrict__ bias,
                                                int M, int NC, int S,
                                                ushort* __restrict__ bt) {
  const size_t idx = (size_t)blockIdx.x * 256 + threadIdx.x;
  const size_t tot = (size_t)M * NC;
  float s = 0.f;
  for (int p = 0; p < S; ++p) s += P[p * tot + idx];
  const int r = (int)(idx / NC), c = (int)(idx % NC);
  float v = s * rs[r] + bias[c];
  if constexpr (MODE == 3) v = v > 0.f ? v : 0.f;
  if (C) C[idx] = v;
  if constexpr (EMIT == 2) bt[idx] = f2b(v);
}

// ---------------------------------------------------------------- launcher
extern "C" void kernel_launch(void* const* d_in, const int* in_sizes, int n_in,
                              void* d_out, int out_size, void* d_ws, size_t ws_size,
                              hipStream_t stream) {
  const float* input = (const float*)d_in[0];
  const float* Adj   = (const float*)d_in[1];
  const float* unc   = (const float*)d_in[2];
  const float* w1    = (const float*)d_in[3];
  const float* w2    = (const float*)d_in[4];
  const float* delta = (const float*)d_in[5];
  const float* W1    = (const float*)d_in[6];
  const float* b1    = (const float*)d_in[7];
  const float* W2    = (const float*)d_in[8];
  const float* b2    = (const float*)d_in[9];

  float* xout = (float*)d_out;
  float* anew = xout + (size_t)NN * CCC;
  float* afin = anew + (size_t)NN * NN;

  float* w = (float*)d_ws;
  size_t o = 0;
  float* DINV  = w + o; o += NN;
  float* DSQ   = w + o; o += NN;
  float* EARR  = w + o; o += NN;
  float* DINV2 = w + o; o += NN;
  int*   FLAG  = (int*)(w + o);
  int*   CNT   = FLAG + 16; o += NN;
  // union region: gated scratch chain OR bf16 A_final sidecar (chain dead by then)
  float* REGION = w + o; o += (size_t)NN * NN / 2;          // NN*NN ushorts
  float* X1   = REGION;
  float* X2   = X1 + (size_t)NN * FF;
  float* EMBP = X2 + (size_t)NN * FF;
  float* EMBN = EMBP + (size_t)NN * FF;
  float* VALS = EMBN + (size_t)NN * FF;
  int*   IDX  = (int*)(VALS + (size_t)NN * KTOP);
  ushort* AFINB = (ushort*)REGION;
  ushort* Y1T    = (ushort*)(w + o); o += (size_t)NN * HH / 2;    // [128][6144]
  ushort* XRELUB = (ushort*)(w + o); o += (size_t)NN * HH / 2;    // [6144][128]
  ushort* Y2T    = (ushort*)(w + o); o += (size_t)NN * CCC / 2;   // [16][6144]
  ushort* W1T    = (ushort*)(w + o); o += (size_t)FF * HH / 2;    // [128][512]
  ushort* W2T    = (ushort*)(w + o); o += (size_t)HH * CCC / 2 + 64;
  float* PK      = w + o; o += (size_t)4 * NN * HH;               // split-K partials (12.6 MB)

  // 0. A_new = 0 via pure-write fill (~7 TB/s); gated chain re-zeroes+scatters if live
  hipMemsetAsync(anew, 0, (size_t)NN * NN * sizeof(float), stream);

  // 1. flag + e + weight transposes + barrier-counter reset
  k_flag_prep<<<257, 256, 0, stream>>>(unc, delta, EARR, FLAG, CNT, W1, W2, W1T, W2T);

  // 2. gated graph-revision chain (single dispatch; immediate exit when gate==0)
  k_gated_chain<<<GCB, 256, 0, stream>>>(Adj, input, w1, w2, DINV, DSQ, X1, X2, EMBP, EMBN,
                                         afin, anew, VALS, IDX, CNT, FLAG);

  // 3. A_final/row-sum/bf16-sidecar stream (gate==0: pure copy+cast+sum, no anew traffic)
  k_mask_final<<<NN, 256, 0, stream>>>(anew, Adj, EARR, delta, afin, AFINB, DINV2, FLAG);

  // 4-9. task GCN, all-MFMA
  k_gA<<<192, 256, 0, stream>>>(input, W1T, DINV2, Y1T);
  k_gB<4><<<dim3(192, 1, 4), 256, 0, stream>>>(AFINB, Y1T, PK);
  k_reduce<3, 2><<<(NN * HH) / 256, 256, 0, stream>>>(PK, nullptr, DINV2, b1, NN, HH, 4, XRELUB);
  k_gC<<<96, 256, 0, stream>>>(XRELUB, W2T, DINV2, Y2T);
  k_gD<16><<<dim3(96, 1, 16), 256, 0, stream>>>(AFINB, Y2T, PK);
  k_reduce<4, 0><<<(NN * CCC) / 256, 256, 0, stream>>>(PK, xout, DINV2, b2, NN, CCC, 16, nullptr);
}